// Round 2
// baseline (482.704 us; speedup 1.0000x reference)
//
#include <hip/hip_runtime.h>
#include <hip/hip_bf16.h>

// ---- degree: deg[dst] += 1 per edge ----
__global__ void deg_kernel(const int* __restrict__ dst, float* __restrict__ deg, int E) {
    int e = blockIdx.x * blockDim.x + threadIdx.x;
    if (e < E) atomicAdd(&deg[dst[e]], 1.0f);
}

// ---- dis = deg > 0 ? deg^-0.5 : 0 (in-place) ----
__global__ void dis_kernel(float* __restrict__ deg, int n) {
    int i = blockIdx.x * blockDim.x + threadIdx.x;
    if (i < n) {
        float d = deg[i];
        deg[i] = (d > 0.0f) ? rsqrtf(d) : 0.0f;
    }
}

// ---- norm[e] = dis[src]*dis[dst] ----
__global__ void norm_kernel(const int* __restrict__ src, const int* __restrict__ dst,
                            const float* __restrict__ dis, float* __restrict__ nrm, int E) {
    int e = blockIdx.x * blockDim.x + threadIdx.x;
    if (e < E) nrm[e] = dis[src[e]] * dis[dst[e]];
}

// ---- GEMM1 fused with row-normalize: z_k = rownorm(x) @ W1[k], k=0..3 ----
// x: [n,128] f32, W1: [4,128,16] f32, z: 4 planes of [n,16] f32 (stride nstride)
__global__ __launch_bounds__(256) void gemm1_kernel(
    const float* __restrict__ x, const float* __restrict__ W1,
    float* __restrict__ z, int n, int nstride)
{
    __shared__ float Wlds[128 * 64];   // [d][k*16+oo]
    __shared__ float hlds[4 * 128];    // one row per wave
    for (int j = threadIdx.x; j < 8192; j += 256) {
        int k = j >> 11;        // W1[k][d][oo], strides 2048/16/1
        int r = j & 2047;
        int d = r >> 4;
        int oo = r & 15;
        Wlds[d * 64 + k * 16 + oo] = W1[j];
    }
    __syncthreads();
    int wave = threadIdx.x >> 6;
    int lane = threadIdx.x & 63;
    int ngroups = (n + 3) >> 2;
    for (int g = blockIdx.x; g < ngroups; g += gridDim.x) {
        int row = g * 4 + wave;
        if (row < n) {
            float a0 = x[row * 128 + lane];
            float a1 = x[row * 128 + 64 + lane];
            float s = a0 + a1;
            #pragma unroll
            for (int off = 32; off > 0; off >>= 1) s += __shfl_down(s, off, 64);
            s = __shfl(s, 0, 64);                 // row sum
            float scale = 1.0f / fmaxf(s, 1e-8f); // clip(sum, 1e-8, None)
            hlds[wave * 128 + lane]      = a0 * scale;
            hlds[wave * 128 + 64 + lane] = a1 * scale;
        }
        __syncthreads();
        if (row < n) {
            float acc = 0.0f;
            #pragma unroll 8
            for (int d = 0; d < 128; ++d)
                acc += hlds[wave * 128 + d] * Wlds[d * 64 + lane];
            z[(lane >> 4) * nstride + row * 16 + (lane & 15)] = acc;
        }
        __syncthreads();
    }
}

// ---- edge-parallel SpMM (width 16): out[dst,:] += w * in[src,:] ----
// w = nrm[e] if nrm != null else dis[src]*dis[dst]
__global__ __launch_bounds__(256) void spmm_kernel(
    const float* __restrict__ in, float* __restrict__ out,
    const int* __restrict__ src, const int* __restrict__ dst,
    const float* __restrict__ nrm, const float* __restrict__ dis, int E)
{
    int t = blockIdx.x * blockDim.x + threadIdx.x;
    int e = t >> 4;
    int f = t & 15;
    if (e < E) {
        int s = src[e], d = dst[e];
        float w = nrm ? nrm[e] : dis[s] * dis[d];
        atomicAdd(&out[d * 16 + f], w * in[s * 16 + f]);
    }
}

// ---- h1 = relu(z0 + b1), in place ----
__global__ void bias_relu_kernel(float* __restrict__ z0, const float* __restrict__ b, int total) {
    int i = blockIdx.x * blockDim.x + threadIdx.x;
    if (i < total) {
        float v = z0[i] + b[i & 15];
        z0[i] = v > 0.0f ? v : 0.0f;
    }
}

// ---- GEMM2: out[n,64] = b2 + sum_{k,d} G_k[n,d] * W2[k,d,:] ----
// z holds 4 planes [n,16] f32; W2 flat [4,16,64] is already [(k*16+d)][o]
__global__ __launch_bounds__(256) void gemm2_kernel(
    const float* __restrict__ z, const float* __restrict__ W2,
    const float* __restrict__ bias2, float* __restrict__ out, int n, int nstride)
{
    __shared__ float Wlds[64 * 64];
    __shared__ float rlds[4 * 64];
    for (int j = threadIdx.x; j < 4096; j += 256)
        Wlds[j] = W2[j];
    __syncthreads();
    int wave = threadIdx.x >> 6;
    int lane = threadIdx.x & 63;
    float bias = bias2[lane];
    int ngroups = (n + 3) >> 2;
    for (int g = blockIdx.x; g < ngroups; g += gridDim.x) {
        int row = g * 4 + wave;
        if (row < n)
            rlds[wave * 64 + lane] = z[(lane >> 4) * nstride + row * 16 + (lane & 15)];
        __syncthreads();
        if (row < n) {
            float acc = bias;
            #pragma unroll 8
            for (int j = 0; j < 64; ++j)
                acc += rlds[wave * 64 + j] * Wlds[j * 64 + lane];
            out[row * 64 + lane] = acc;
        }
        __syncthreads();
    }
}

extern "C" void kernel_launch(void* const* d_in, const int* in_sizes, int n_in,
                              void* d_out, int out_size, void* d_ws, size_t ws_size,
                              hipStream_t stream) {
    const float* x   = (const float*)d_in[0];
    const int*   ei  = (const int*)d_in[1];
    const float* W1  = (const float*)d_in[2];
    const float* b1  = (const float*)d_in[3];
    const float* W2  = (const float*)d_in[4];
    const float* bb2 = (const float*)d_in[5];
    float* out = (float*)d_out;

    const int n = in_sizes[0] / 128;   // 50000
    const int E = in_sizes[1] / 2;     // 800000
    const int NS = n * 16;

    float* ws   = (float*)d_ws;
    float* dis  = ws;                          // n floats (deg then deg^-1/2)
    float* z    = ws + ((n + 127) & ~127);     // 4 * NS floats
    float* nrm  = z + 4 * NS;                  // E floats (optional)
    size_t need_with_nrm = (size_t)(((n + 127) & ~127) + 4 * NS + E) * sizeof(float);
    bool use_nrm = (ws_size >= need_with_nrm);
    const float* nrm_arg = use_nrm ? nrm : nullptr;

    const int* srcp = ei;
    const int* dstp = ei + E;

    // gcn_norm
    hipMemsetAsync(dis, 0, n * sizeof(float), stream);
    deg_kernel<<<(E + 255) / 256, 256, 0, stream>>>(dstp, dis, E);
    dis_kernel<<<(n + 255) / 256, 256, 0, stream>>>(dis, n);
    if (use_nrm)
        norm_kernel<<<(E + 255) / 256, 256, 0, stream>>>(srcp, dstp, dis, nrm, E);

    // layer 1: z_k = rownorm(x) @ W1[k]
    gemm1_kernel<<<512, 256, 0, stream>>>(x, W1, z, n, NS);

    // Horner: z2 += A z3; z1 += A z2; z0 += A z1  (all width-16 SpMMs)
    int spmm_blocks = (E * 16 + 255) / 256;
    spmm_kernel<<<spmm_blocks, 256, 0, stream>>>(z + 3 * NS, z + 2 * NS, srcp, dstp, nrm_arg, dis, E);
    spmm_kernel<<<spmm_blocks, 256, 0, stream>>>(z + 2 * NS, z + 1 * NS, srcp, dstp, nrm_arg, dis, E);
    spmm_kernel<<<spmm_blocks, 256, 0, stream>>>(z + 1 * NS, z,          srcp, dstp, nrm_arg, dis, E);

    // h1 = relu(z0 + b1) in place
    bias_relu_kernel<<<(NS + 255) / 256, 256, 0, stream>>>(z, b1, NS);

    // layer 2 hops: g1 = A h1; g2 = A g1; g3 = A g2 (into zeroed planes 1..3)
    hipMemsetAsync(z + NS, 0, (size_t)3 * NS * sizeof(float), stream);
    spmm_kernel<<<spmm_blocks, 256, 0, stream>>>(z,          z + NS,     srcp, dstp, nrm_arg, dis, E);
    spmm_kernel<<<spmm_blocks, 256, 0, stream>>>(z + NS,     z + 2 * NS, srcp, dstp, nrm_arg, dis, E);
    spmm_kernel<<<spmm_blocks, 256, 0, stream>>>(z + 2 * NS, z + 3 * NS, srcp, dstp, nrm_arg, dis, E);

    // out = cat(h1, g1, g2, g3) @ W2cat + b2
    gemm2_kernel<<<512, 256, 0, stream>>>(z, W2, bb2, out, n, NS);
}

// Round 3
// 417.979 us; speedup vs baseline: 1.1549x; 1.1549x over previous
//
#include <hip/hip_runtime.h>
#include <hip/hip_bf16.h>

// ---- degree histogram: deg[dst] += 1 per edge ----
__global__ void deg_kernel(const int* __restrict__ dst, float* __restrict__ deg, int E) {
    int e = blockIdx.x * blockDim.x + threadIdx.x;
    if (e < E) atomicAdd(&deg[dst[e]], 1.0f);
}

// ---- dis = deg > 0 ? deg^-0.5 : 0 (in-place) ----
__global__ void dis_kernel(float* __restrict__ deg, int n) {
    int i = blockIdx.x * blockDim.x + threadIdx.x;
    if (i < n) {
        float d = deg[i];
        deg[i] = (d > 0.0f) ? rsqrtf(d) : 0.0f;
    }
}

// ---- single-block exclusive scan: rowptr[0..n] from deg counts ----
__global__ __launch_bounds__(1024) void scan_kernel(const float* __restrict__ deg,
                                                    int* __restrict__ rowptr, int n) {
    __shared__ int part[1024];
    int tid = threadIdx.x;
    int chunk = (n + 1023) / 1024;
    int beg = tid * chunk;
    int end = beg + chunk; if (end > n) end = n;
    int s = 0;
    for (int i = beg; i < end; ++i) s += (int)deg[i];
    part[tid] = s;
    __syncthreads();
    for (int off = 1; off < 1024; off <<= 1) {
        int v = (tid >= off) ? part[tid - off] : 0;
        __syncthreads();
        part[tid] += v;
        __syncthreads();
    }
    int run = (tid > 0) ? part[tid - 1] : 0;
    if (tid == 0) rowptr[0] = 0;
    for (int i = beg; i < end; ++i) { run += (int)deg[i]; rowptr[i + 1] = run; }
}

// ---- scatter edges into CSR: ecolw[pos] = {src_bits, dis[src]*dis[dst]} ----
__global__ void scatter_kernel(const int* __restrict__ src, const int* __restrict__ dst,
                               const float* __restrict__ dis, const int* __restrict__ rowptr,
                               int* __restrict__ cnt, float2* __restrict__ ecolw, int E) {
    int e = blockIdx.x * blockDim.x + threadIdx.x;
    if (e < E) {
        int s = src[e], d = dst[e];
        int pos = atomicAdd(&cnt[d], 1);
        ecolw[rowptr[d] + pos] = make_float2(__int_as_float(s), dis[s] * dis[d]);
    }
}

// ---- GEMM1: z_k = rownorm(x) @ W1[k].  rownorm commutes: (x/S)W = (xW)/S ----
// One wave per row; row is wave-uniform (readfirstlane) -> scalar x loads;
// W column per lane in 128 VGPRs. No LDS, no barriers.
__global__ __launch_bounds__(256) void gemm1_kernel(
    const float* __restrict__ x, const float* __restrict__ W1,
    float* __restrict__ z, int n, int nstride)
{
    int lane = threadIdx.x & 63;
    int k = lane >> 4, oo = lane & 15;
    float wr[128];
    #pragma unroll
    for (int d = 0; d < 128; ++d)
        wr[d] = W1[k * 2048 + d * 16 + oo];     // W1[k][d][oo]
    int wid = blockIdx.x * (blockDim.x >> 6) + (threadIdx.x >> 6);
    int nw  = gridDim.x * (blockDim.x >> 6);
    for (int row = wid; row < n; row += nw) {
        int urow = __builtin_amdgcn_readfirstlane(row);
        const float4* xr = (const float4*)(x + (long)urow * 128);
        float acc0 = 0.f, acc1 = 0.f, sum0 = 0.f, sum1 = 0.f;
        #pragma unroll
        for (int j = 0; j < 32; j += 2) {
            float4 a = xr[j], b = xr[j + 1];
            acc0 += a.x * wr[4*j+0] + a.y * wr[4*j+1] + a.z * wr[4*j+2] + a.w * wr[4*j+3];
            acc1 += b.x * wr[4*j+4] + b.y * wr[4*j+5] + b.z * wr[4*j+6] + b.w * wr[4*j+7];
            sum0 += (a.x + a.y) + (a.z + a.w);
            sum1 += (b.x + b.y) + (b.z + b.w);
        }
        float scale = 1.0f / fmaxf(sum0 + sum1, 1e-8f);
        z[(long)k * nstride + (long)urow * 16 + oo] = (acc0 + acc1) * scale;
    }
}

// ---- CSR SpMM (width 16): out[r,:] = sum_e w[e]*in[col[e],:] (+addsrc)(+b)(relu) ----
__global__ __launch_bounds__(256) void spmm_csr_kernel(
    const float* __restrict__ in, const float* __restrict__ addsrc,
    float* __restrict__ out, const int* __restrict__ rowptr,
    const float2* __restrict__ ecolw, const float* __restrict__ b,
    int relu, int n)
{
    int t = blockIdx.x * blockDim.x + threadIdx.x;
    int r = t >> 4, f = t & 15;
    if (r >= n) return;
    int e0 = rowptr[r], e1 = rowptr[r + 1];
    float acc0 = 0.f, acc1 = 0.f;
    int e = e0;
    for (; e + 2 <= e1; e += 2) {
        float2 c0 = ecolw[e], c1 = ecolw[e + 1];
        acc0 += c0.y * in[__float_as_int(c0.x) * 16 + f];
        acc1 += c1.y * in[__float_as_int(c1.x) * 16 + f];
    }
    if (e < e1) {
        float2 c0 = ecolw[e];
        acc0 += c0.y * in[__float_as_int(c0.x) * 16 + f];
    }
    float acc = acc0 + acc1;
    if (addsrc) acc += addsrc[r * 16 + f];
    if (b)      acc += b[f];
    if (relu)   acc = fmaxf(acc, 0.f);
    out[r * 16 + f] = acc;
}

// ---- GEMM2: out[n,64] = cat(planes) @ W2cat + b2, same scalar-broadcast scheme ----
__global__ __launch_bounds__(256) void gemm2_kernel(
    const float* __restrict__ z, const float* __restrict__ W2,
    const float* __restrict__ b2, float* __restrict__ out, int n, int nstride)
{
    int lane = threadIdx.x & 63;
    float wr[64];
    #pragma unroll
    for (int j = 0; j < 64; ++j) wr[j] = W2[j * 64 + lane];
    float bias = b2[lane];
    int wid = blockIdx.x * (blockDim.x >> 6) + (threadIdx.x >> 6);
    int nw  = gridDim.x * (blockDim.x >> 6);
    for (int row = wid; row < n; row += nw) {
        int urow = __builtin_amdgcn_readfirstlane(row);
        float acc0 = 0.f, acc1 = 0.f;
        #pragma unroll
        for (int p = 0; p < 4; ++p) {
            const float4* zr = (const float4*)(z + (long)p * nstride + (long)urow * 16);
            float4 a = zr[0], bb = zr[1], c = zr[2], d = zr[3];
            acc0 += a.x  * wr[p*16+ 0] + a.y  * wr[p*16+ 1] + a.z  * wr[p*16+ 2] + a.w  * wr[p*16+ 3];
            acc1 += bb.x * wr[p*16+ 4] + bb.y * wr[p*16+ 5] + bb.z * wr[p*16+ 6] + bb.w * wr[p*16+ 7];
            acc0 += c.x  * wr[p*16+ 8] + c.y  * wr[p*16+ 9] + c.z  * wr[p*16+10] + c.w  * wr[p*16+11];
            acc1 += d.x  * wr[p*16+12] + d.y  * wr[p*16+13] + d.z  * wr[p*16+14] + d.w  * wr[p*16+15];
        }
        out[(long)urow * 64 + lane] = acc0 + acc1 + bias;
    }
}

// ---- fallback: edge-parallel atomic SpMM with on-the-fly norm ----
__global__ __launch_bounds__(256) void spmm_atomic_kernel(
    const float* __restrict__ in, float* __restrict__ out,
    const int* __restrict__ src, const int* __restrict__ dst,
    const float* __restrict__ dis, int E)
{
    int t = blockIdx.x * blockDim.x + threadIdx.x;
    int e = t >> 4, f = t & 15;
    if (e < E) {
        int s = src[e], d = dst[e];
        atomicAdd(&out[d * 16 + f], dis[s] * dis[d] * in[s * 16 + f]);
    }
}

__global__ void bias_relu_kernel(float* __restrict__ z0, const float* __restrict__ b, int total) {
    int i = blockIdx.x * blockDim.x + threadIdx.x;
    if (i < total) {
        float v = z0[i] + b[i & 15];
        z0[i] = v > 0.0f ? v : 0.0f;
    }
}

extern "C" void kernel_launch(void* const* d_in, const int* in_sizes, int n_in,
                              void* d_out, int out_size, void* d_ws, size_t ws_size,
                              hipStream_t stream) {
    const float* x   = (const float*)d_in[0];
    const int*   ei  = (const int*)d_in[1];
    const float* W1  = (const float*)d_in[2];
    const float* b1  = (const float*)d_in[3];
    const float* W2  = (const float*)d_in[4];
    const float* bb2 = (const float*)d_in[5];
    float* out = (float*)d_out;

    const int n  = in_sizes[0] / 128;   // 50000
    const int E  = in_sizes[1] / 2;     // 800000
    const int NS = n * 16;

    const int* srcp = ei;
    const int* dstp = ei + E;

    float* ws = (float*)d_ws;
    // layout: deg/dis [n] | rowptr [n+1] | cnt [n] | (pad) | z [4*NS] | ecolw [2*E]
    float* deg    = ws;
    int*   rowptr = (int*)(ws + n);
    int*   cnt    = (int*)(ws + 2 * n + 1);
    size_t zoff   = ((size_t)(3 * n + 2) + 3) & ~(size_t)3;   // 16B align
    float* z      = ws + zoff;
    float2* ecolw = (float2*)(z + 4 * (size_t)NS);
    size_t need   = (zoff + 4 * (size_t)NS + 2 * (size_t)E) * sizeof(float);

    if (ws_size >= need) {
        // ---------- CSR path ----------
        hipMemsetAsync(ws, 0, (size_t)(3 * n + 2) * sizeof(float), stream);  // deg + rowptr + cnt
        deg_kernel<<<(E + 255) / 256, 256, 0, stream>>>(dstp, deg, E);
        scan_kernel<<<1, 1024, 0, stream>>>(deg, rowptr, n);
        dis_kernel<<<(n + 255) / 256, 256, 0, stream>>>(deg, n);             // deg -> dis in place
        scatter_kernel<<<(E + 255) / 256, 256, 0, stream>>>(srcp, dstp, deg, rowptr, cnt, ecolw, E);

        gemm1_kernel<<<1024, 256, 0, stream>>>(x, W1, z, n, NS);

        int sb = (16 * n + 255) / 256;
        // Horner layer 1
        spmm_csr_kernel<<<sb, 256, 0, stream>>>(z + 3 * NS, z + 2 * NS, z + 2 * NS, rowptr, ecolw, nullptr, 0, n);
        spmm_csr_kernel<<<sb, 256, 0, stream>>>(z + 2 * NS, z + 1 * NS, z + 1 * NS, rowptr, ecolw, nullptr, 0, n);
        spmm_csr_kernel<<<sb, 256, 0, stream>>>(z + 1 * NS, z,          z,          rowptr, ecolw, b1,      1, n);
        // layer 2 hops
        spmm_csr_kernel<<<sb, 256, 0, stream>>>(z,          nullptr, z + 1 * NS, rowptr, ecolw, nullptr, 0, n);
        spmm_csr_kernel<<<sb, 256, 0, stream>>>(z + 1 * NS, nullptr, z + 2 * NS, rowptr, ecolw, nullptr, 0, n);
        spmm_csr_kernel<<<sb, 256, 0, stream>>>(z + 2 * NS, nullptr, z + 3 * NS, rowptr, ecolw, nullptr, 0, n);

        gemm2_kernel<<<1024, 256, 0, stream>>>(z, W2, bb2, out, n, NS);
    } else {
        // ---------- fallback: atomic path (dis [n] | z [4*NS]) ----------
        float* dis2 = ws;
        size_t z2off = ((size_t)n + 3) & ~(size_t)3;
        float* z2 = ws + z2off;
        hipMemsetAsync(dis2, 0, n * sizeof(float), stream);
        deg_kernel<<<(E + 255) / 256, 256, 0, stream>>>(dstp, dis2, E);
        dis_kernel<<<(n + 255) / 256, 256, 0, stream>>>(dis2, n);
        gemm1_kernel<<<1024, 256, 0, stream>>>(x, W1, z2, n, NS);
        int sb = (16 * E + 255) / 256;
        spmm_atomic_kernel<<<sb, 256, 0, stream>>>(z2 + 3 * NS, z2 + 2 * NS, srcp, dstp, dis2, E);
        spmm_atomic_kernel<<<sb, 256, 0, stream>>>(z2 + 2 * NS, z2 + 1 * NS, srcp, dstp, dis2, E);
        spmm_atomic_kernel<<<sb, 256, 0, stream>>>(z2 + 1 * NS, z2,          srcp, dstp, dis2, E);
        bias_relu_kernel<<<(NS + 255) / 256, 256, 0, stream>>>(z2, b1, NS);
        hipMemsetAsync(z2 + NS, 0, (size_t)3 * NS * sizeof(float), stream);
        spmm_atomic_kernel<<<sb, 256, 0, stream>>>(z2,          z2 + NS,     srcp, dstp, dis2, E);
        spmm_atomic_kernel<<<sb, 256, 0, stream>>>(z2 + NS,     z2 + 2 * NS, srcp, dstp, dis2, E);
        spmm_atomic_kernel<<<sb, 256, 0, stream>>>(z2 + 2 * NS, z2 + 3 * NS, srcp, dstp, dis2, E);
        gemm2_kernel<<<1024, 256, 0, stream>>>(z2, W2, bb2, out, n, NS);
    }
}

// Round 4
// 337.060 us; speedup vs baseline: 1.4321x; 1.2401x over previous
//
#include <hip/hip_runtime.h>
#include <hip/hip_bf16.h>

// ---- degree histogram: deg[dst] += 1 per edge ----
__global__ void deg_kernel(const int* __restrict__ dst, float* __restrict__ deg, int E) {
    int e = blockIdx.x * blockDim.x + threadIdx.x;
    if (e < E) atomicAdd(&deg[dst[e]], 1.0f);
}

// ---- dis = deg > 0 ? deg^-0.5 : 0 (in-place) ----
__global__ void dis_kernel(float* __restrict__ deg, int n) {
    int i = blockIdx.x * blockDim.x + threadIdx.x;
    if (i < n) {
        float d = deg[i];
        deg[i] = (d > 0.0f) ? rsqrtf(d) : 0.0f;
    }
}

// ---- hierarchical scan pass A: per-block inclusive scan + block sums ----
__global__ __launch_bounds__(256) void scanA_kernel(const float* __restrict__ deg,
                                                    int* __restrict__ rowptr,
                                                    int* __restrict__ bsum, int n) {
    __shared__ int lds[256];
    int i = blockIdx.x * 256 + threadIdx.x;
    int v = (i < n) ? (int)deg[i] : 0;
    lds[threadIdx.x] = v;
    __syncthreads();
    #pragma unroll
    for (int off = 1; off < 256; off <<= 1) {
        int t = (threadIdx.x >= off) ? lds[threadIdx.x - off] : 0;
        __syncthreads();
        lds[threadIdx.x] += t;
        __syncthreads();
    }
    if (i < n) rowptr[i + 1] = lds[threadIdx.x];
    if (threadIdx.x == 255) bsum[blockIdx.x] = lds[255];
}

// ---- pass B: single-block exclusive scan of block sums (nb <= 1024) ----
__global__ __launch_bounds__(1024) void scanB_kernel(int* __restrict__ bsum, int nb) {
    __shared__ int lds[1024];
    int t = threadIdx.x;
    int v = (t < nb) ? bsum[t] : 0;
    lds[t] = v;
    __syncthreads();
    #pragma unroll
    for (int off = 1; off < 1024; off <<= 1) {
        int u = (t >= off) ? lds[t - off] : 0;
        __syncthreads();
        lds[t] += u;
        __syncthreads();
    }
    if (t < nb) bsum[t] = lds[t] - v;   // inclusive - self = exclusive
}

// ---- pass C: add block offsets ----
__global__ __launch_bounds__(256) void scanC_kernel(int* __restrict__ rowptr,
                                                    const int* __restrict__ bsum, int n) {
    int i = blockIdx.x * 256 + threadIdx.x;
    if (i < n) rowptr[i + 1] += bsum[blockIdx.x];
    if (i == 0) rowptr[0] = 0;
}

// ---- fallback single-block scan (only if n > 262144) ----
__global__ __launch_bounds__(1024) void scan_kernel(const float* __restrict__ deg,
                                                    int* __restrict__ rowptr, int n) {
    __shared__ int part[1024];
    int tid = threadIdx.x;
    int chunk = (n + 1023) / 1024;
    int beg = tid * chunk;
    int end = beg + chunk; if (end > n) end = n;
    int s = 0;
    for (int i = beg; i < end; ++i) s += (int)deg[i];
    part[tid] = s;
    __syncthreads();
    for (int off = 1; off < 1024; off <<= 1) {
        int v = (tid >= off) ? part[tid - off] : 0;
        __syncthreads();
        part[tid] += v;
        __syncthreads();
    }
    int run = (tid > 0) ? part[tid - 1] : 0;
    if (tid == 0) rowptr[0] = 0;
    for (int i = beg; i < end; ++i) { run += (int)deg[i]; rowptr[i + 1] = run; }
}

// ---- scatter edges into CSR: ecolw[pos] = {src_bits, dis[src]*dis[dst]} ----
__global__ void scatter_kernel(const int* __restrict__ src, const int* __restrict__ dst,
                               const float* __restrict__ dis, const int* __restrict__ rowptr,
                               int* __restrict__ cnt, float2* __restrict__ ecolw, int E) {
    int e = blockIdx.x * blockDim.x + threadIdx.x;
    if (e < E) {
        int s = src[e], d = dst[e];
        int pos = atomicAdd(&cnt[d], 1);
        ecolw[rowptr[d] + pos] = make_float2(__int_as_float(s), dis[s] * dis[d]);
    }
}

// ---- GEMM1: z_k = rownorm(x) @ W1[k].  rownorm commutes: (x/S)W = (xW)/S ----
__global__ __launch_bounds__(256) void gemm1_kernel(
    const float* __restrict__ x, const float* __restrict__ W1,
    float* __restrict__ z, int n, int nstride)
{
    int lane = threadIdx.x & 63;
    int k = lane >> 4, oo = lane & 15;
    float wr[128];
    #pragma unroll
    for (int d = 0; d < 128; ++d)
        wr[d] = W1[k * 2048 + d * 16 + oo];     // W1[k][d][oo]
    int wid = blockIdx.x * (blockDim.x >> 6) + (threadIdx.x >> 6);
    int nw  = gridDim.x * (blockDim.x >> 6);
    for (int row = wid; row < n; row += nw) {
        int urow = __builtin_amdgcn_readfirstlane(row);
        const float4* xr = (const float4*)(x + (long)urow * 128);
        float acc0 = 0.f, acc1 = 0.f, sum0 = 0.f, sum1 = 0.f;
        #pragma unroll
        for (int j = 0; j < 32; j += 2) {
            float4 a = xr[j], b = xr[j + 1];
            acc0 += a.x * wr[4*j+0] + a.y * wr[4*j+1] + a.z * wr[4*j+2] + a.w * wr[4*j+3];
            acc1 += b.x * wr[4*j+4] + b.y * wr[4*j+5] + b.z * wr[4*j+6] + b.w * wr[4*j+7];
            sum0 += (a.x + a.y) + (a.z + a.w);
            sum1 += (b.x + b.y) + (b.z + b.w);
        }
        float scale = 1.0f / fmaxf(sum0 + sum1, 1e-8f);
        z[(long)k * nstride + (long)urow * 16 + oo] = (acc0 + acc1) * scale;
    }
}

// ---- CSR SpMM (width 16): out[r,:] = sum_e w[e]*in[col[e],:] (+addsrc)(+b)(relu) ----
__global__ __launch_bounds__(256) void spmm_csr_kernel(
    const float* __restrict__ in, const float* __restrict__ addsrc,
    float* __restrict__ out, const int* __restrict__ rowptr,
    const float2* __restrict__ ecolw, const float* __restrict__ b,
    int relu, int n)
{
    int t = blockIdx.x * blockDim.x + threadIdx.x;
    int r = t >> 4, f = t & 15;
    if (r >= n) return;
    int e0 = rowptr[r], e1 = rowptr[r + 1];
    float acc0 = 0.f, acc1 = 0.f, acc2 = 0.f, acc3 = 0.f;
    int e = e0;
    for (; e + 4 <= e1; e += 4) {
        float2 c0 = ecolw[e], c1 = ecolw[e + 1], c2 = ecolw[e + 2], c3 = ecolw[e + 3];
        acc0 += c0.y * in[__float_as_int(c0.x) * 16 + f];
        acc1 += c1.y * in[__float_as_int(c1.x) * 16 + f];
        acc2 += c2.y * in[__float_as_int(c2.x) * 16 + f];
        acc3 += c3.y * in[__float_as_int(c3.x) * 16 + f];
    }
    for (; e < e1; ++e) {
        float2 c0 = ecolw[e];
        acc0 += c0.y * in[__float_as_int(c0.x) * 16 + f];
    }
    float acc = (acc0 + acc1) + (acc2 + acc3);
    if (addsrc) acc += addsrc[r * 16 + f];
    if (b)      acc += b[f];
    if (relu)   acc = fmaxf(acc, 0.f);
    out[r * 16 + f] = acc;
}

// ---- GEMM2: out[n,64] = cat(planes) @ W2cat + b2, scalar-broadcast scheme ----
__global__ __launch_bounds__(256) void gemm2_kernel(
    const float* __restrict__ z, const float* __restrict__ W2,
    const float* __restrict__ b2, float* __restrict__ out, int n, int nstride)
{
    int lane = threadIdx.x & 63;
    float wr[64];
    #pragma unroll
    for (int j = 0; j < 64; ++j) wr[j] = W2[j * 64 + lane];
    float bias = b2[lane];
    int wid = blockIdx.x * (blockDim.x >> 6) + (threadIdx.x >> 6);
    int nw  = gridDim.x * (blockDim.x >> 6);
    for (int row = wid; row < n; row += nw) {
        int urow = __builtin_amdgcn_readfirstlane(row);
        float acc0 = 0.f, acc1 = 0.f;
        #pragma unroll
        for (int p = 0; p < 4; ++p) {
            const float4* zr = (const float4*)(z + (long)p * nstride + (long)urow * 16);
            float4 a = zr[0], bb = zr[1], c = zr[2], d = zr[3];
            acc0 += a.x  * wr[p*16+ 0] + a.y  * wr[p*16+ 1] + a.z  * wr[p*16+ 2] + a.w  * wr[p*16+ 3];
            acc1 += bb.x * wr[p*16+ 4] + bb.y * wr[p*16+ 5] + bb.z * wr[p*16+ 6] + bb.w * wr[p*16+ 7];
            acc0 += c.x  * wr[p*16+ 8] + c.y  * wr[p*16+ 9] + c.z  * wr[p*16+10] + c.w  * wr[p*16+11];
            acc1 += d.x  * wr[p*16+12] + d.y  * wr[p*16+13] + d.z  * wr[p*16+14] + d.w  * wr[p*16+15];
        }
        out[(long)urow * 64 + lane] = acc0 + acc1 + bias;
    }
}

// ---- fallback: edge-parallel atomic SpMM with on-the-fly norm ----
__global__ __launch_bounds__(256) void spmm_atomic_kernel(
    const float* __restrict__ in, float* __restrict__ out,
    const int* __restrict__ src, const int* __restrict__ dst,
    const float* __restrict__ dis, int E)
{
    int t = blockIdx.x * blockDim.x + threadIdx.x;
    int e = t >> 4, f = t & 15;
    if (e < E) {
        int s = src[e], d = dst[e];
        atomicAdd(&out[d * 16 + f], dis[s] * dis[d] * in[s * 16 + f]);
    }
}

__global__ void bias_relu_kernel(float* __restrict__ z0, const float* __restrict__ b, int total) {
    int i = blockIdx.x * blockDim.x + threadIdx.x;
    if (i < total) {
        float v = z0[i] + b[i & 15];
        z0[i] = v > 0.0f ? v : 0.0f;
    }
}

extern "C" void kernel_launch(void* const* d_in, const int* in_sizes, int n_in,
                              void* d_out, int out_size, void* d_ws, size_t ws_size,
                              hipStream_t stream) {
    const float* x   = (const float*)d_in[0];
    const int*   ei  = (const int*)d_in[1];
    const float* W1  = (const float*)d_in[2];
    const float* b1  = (const float*)d_in[3];
    const float* W2  = (const float*)d_in[4];
    const float* bb2 = (const float*)d_in[5];
    float* out = (float*)d_out;

    const int n  = in_sizes[0] / 128;   // 50000
    const int E  = in_sizes[1] / 2;     // 800000
    const int NS = n * 16;

    const int* srcp = ei;
    const int* dstp = ei + E;

    float* ws = (float*)d_ws;
    // layout: deg/dis [n] | rowptr [n+1] | cnt [n] | bsum [1024] | (pad) | z [4*NS] | ecolw [2*E]
    float* deg    = ws;
    int*   rowptr = (int*)(ws + n);
    int*   cnt    = (int*)(ws + 2 * n + 1);
    int*   bsum   = (int*)(ws + 3 * n + 1);
    size_t zoff   = ((size_t)(3 * n + 1 + 1024) + 3) & ~(size_t)3;   // 16B align
    float* z      = ws + zoff;
    float2* ecolw = (float2*)(z + 4 * (size_t)NS);
    size_t need   = (zoff + 4 * (size_t)NS + 2 * (size_t)E) * sizeof(float);

    if (ws_size >= need) {
        // ---------- CSR path ----------
        int nb = (n + 255) / 256;
        hipMemsetAsync(ws, 0, (size_t)(3 * n + 1 + 1024) * sizeof(float), stream);
        deg_kernel<<<(E + 255) / 256, 256, 0, stream>>>(dstp, deg, E);
        if (nb <= 1024) {
            scanA_kernel<<<nb, 256, 0, stream>>>(deg, rowptr, bsum, n);
            scanB_kernel<<<1, 1024, 0, stream>>>(bsum, nb);
            scanC_kernel<<<nb, 256, 0, stream>>>(rowptr, bsum, n);
        } else {
            scan_kernel<<<1, 1024, 0, stream>>>(deg, rowptr, n);
        }
        dis_kernel<<<(n + 255) / 256, 256, 0, stream>>>(deg, n);   // deg -> dis in place
        scatter_kernel<<<(E + 255) / 256, 256, 0, stream>>>(srcp, dstp, deg, rowptr, cnt, ecolw, E);

        gemm1_kernel<<<1024, 256, 0, stream>>>(x, W1, z, n, NS);

        int sb = (16 * n + 255) / 256;
        // Horner layer 1
        spmm_csr_kernel<<<sb, 256, 0, stream>>>(z + 3 * NS, z + 2 * NS, z + 2 * NS, rowptr, ecolw, nullptr, 0, n);
        spmm_csr_kernel<<<sb, 256, 0, stream>>>(z + 2 * NS, z + 1 * NS, z + 1 * NS, rowptr, ecolw, nullptr, 0, n);
        spmm_csr_kernel<<<sb, 256, 0, stream>>>(z + 1 * NS, z,          z,          rowptr, ecolw, b1,      1, n);
        // layer 2 hops
        spmm_csr_kernel<<<sb, 256, 0, stream>>>(z,          nullptr, z + 1 * NS, rowptr, ecolw, nullptr, 0, n);
        spmm_csr_kernel<<<sb, 256, 0, stream>>>(z + 1 * NS, nullptr, z + 2 * NS, rowptr, ecolw, nullptr, 0, n);
        spmm_csr_kernel<<<sb, 256, 0, stream>>>(z + 2 * NS, nullptr, z + 3 * NS, rowptr, ecolw, nullptr, 0, n);

        gemm2_kernel<<<1024, 256, 0, stream>>>(z, W2, bb2, out, n, NS);
    } else {
        // ---------- fallback: atomic path (dis [n] | z [4*NS]) ----------
        float* dis2 = ws;
        size_t z2off = ((size_t)n + 3) & ~(size_t)3;
        float* z2 = ws + z2off;
        hipMemsetAsync(dis2, 0, n * sizeof(float), stream);
        deg_kernel<<<(E + 255) / 256, 256, 0, stream>>>(dstp, dis2, E);
        dis_kernel<<<(n + 255) / 256, 256, 0, stream>>>(dis2, n);
        gemm1_kernel<<<1024, 256, 0, stream>>>(x, W1, z2, n, NS);
        int sb = (16 * E + 255) / 256;
        spmm_atomic_kernel<<<sb, 256, 0, stream>>>(z2 + 3 * NS, z2 + 2 * NS, srcp, dstp, dis2, E);
        spmm_atomic_kernel<<<sb, 256, 0, stream>>>(z2 + 2 * NS, z2 + 1 * NS, srcp, dstp, dis2, E);
        spmm_atomic_kernel<<<sb, 256, 0, stream>>>(z2 + 1 * NS, z2,          srcp, dstp, dis2, E);
        bias_relu_kernel<<<(NS + 255) / 256, 256, 0, stream>>>(z2, b1, NS);
        hipMemsetAsync(z2 + NS, 0, (size_t)3 * NS * sizeof(float), stream);
        spmm_atomic_kernel<<<sb, 256, 0, stream>>>(z2,          z2 + NS,     srcp, dstp, dis2, E);
        spmm_atomic_kernel<<<sb, 256, 0, stream>>>(z2 + NS,     z2 + 2 * NS, srcp, dstp, dis2, E);
        spmm_atomic_kernel<<<sb, 256, 0, stream>>>(z2 + 2 * NS, z2 + 3 * NS, srcp, dstp, dis2, E);
        gemm2_kernel<<<1024, 256, 0, stream>>>(z2, W2, bb2, out, n, NS);
    }
}

// Round 5
// 328.193 us; speedup vs baseline: 1.4708x; 1.0270x over previous
//
#include <hip/hip_runtime.h>
#include <hip/hip_bf16.h>

// ---- degree histogram: deg[dst] += 1 per edge ----
__global__ void deg_kernel(const int* __restrict__ dst, float* __restrict__ deg, int E) {
    int e = blockIdx.x * blockDim.x + threadIdx.x;
    if (e < E) atomicAdd(&deg[dst[e]], 1.0f);
}

// ---- dis = deg > 0 ? deg^-0.5 : 0 (in-place) ----
__global__ void dis_kernel(float* __restrict__ deg, int n) {
    int i = blockIdx.x * blockDim.x + threadIdx.x;
    if (i < n) {
        float d = deg[i];
        deg[i] = (d > 0.0f) ? rsqrtf(d) : 0.0f;
    }
}

// ---- hierarchical scan pass A: per-block inclusive scan + block sums ----
__global__ __launch_bounds__(256) void scanA_kernel(const float* __restrict__ deg,
                                                    int* __restrict__ rowptr,
                                                    int* __restrict__ bsum, int n) {
    __shared__ int lds[256];
    int i = blockIdx.x * 256 + threadIdx.x;
    int v = (i < n) ? (int)deg[i] : 0;
    lds[threadIdx.x] = v;
    __syncthreads();
    #pragma unroll
    for (int off = 1; off < 256; off <<= 1) {
        int t = (threadIdx.x >= off) ? lds[threadIdx.x - off] : 0;
        __syncthreads();
        lds[threadIdx.x] += t;
        __syncthreads();
    }
    if (i < n) rowptr[i + 1] = lds[threadIdx.x];
    if (threadIdx.x == 255) bsum[blockIdx.x] = lds[255];
}

// ---- pass B: single-block exclusive scan of block sums (nb <= 1024) ----
__global__ __launch_bounds__(1024) void scanB_kernel(int* __restrict__ bsum, int nb) {
    __shared__ int lds[1024];
    int t = threadIdx.x;
    int v = (t < nb) ? bsum[t] : 0;
    lds[t] = v;
    __syncthreads();
    #pragma unroll
    for (int off = 1; off < 1024; off <<= 1) {
        int u = (t >= off) ? lds[t - off] : 0;
        __syncthreads();
        lds[t] += u;
        __syncthreads();
    }
    if (t < nb) bsum[t] = lds[t] - v;   // inclusive - self = exclusive
}

// ---- pass C: add block offsets ----
__global__ __launch_bounds__(256) void scanC_kernel(int* __restrict__ rowptr,
                                                    const int* __restrict__ bsum, int n) {
    int i = blockIdx.x * 256 + threadIdx.x;
    if (i < n) rowptr[i + 1] += bsum[blockIdx.x];
    if (i == 0) rowptr[0] = 0;
}

// ---- fallback single-block scan (only if n > 262144) ----
__global__ __launch_bounds__(1024) void scan_kernel(const float* __restrict__ deg,
                                                    int* __restrict__ rowptr, int n) {
    __shared__ int part[1024];
    int tid = threadIdx.x;
    int chunk = (n + 1023) / 1024;
    int beg = tid * chunk;
    int end = beg + chunk; if (end > n) end = n;
    int s = 0;
    for (int i = beg; i < end; ++i) s += (int)deg[i];
    part[tid] = s;
    __syncthreads();
    for (int off = 1; off < 1024; off <<= 1) {
        int v = (tid >= off) ? part[tid - off] : 0;
        __syncthreads();
        part[tid] += v;
        __syncthreads();
    }
    int run = (tid > 0) ? part[tid - 1] : 0;
    if (tid == 0) rowptr[0] = 0;
    for (int i = beg; i < end; ++i) { run += (int)deg[i]; rowptr[i + 1] = run; }
}

// ---- scatter edges into CSR: ecolw[pos] = {src_bits, dis[src]*dis[dst]} ----
__global__ void scatter_kernel(const int* __restrict__ src, const int* __restrict__ dst,
                               const float* __restrict__ dis, const int* __restrict__ rowptr,
                               int* __restrict__ cnt, float2* __restrict__ ecolw, int E) {
    int e = blockIdx.x * blockDim.x + threadIdx.x;
    if (e < E) {
        int s = src[e], d = dst[e];
        int pos = atomicAdd(&cnt[d], 1);
        ecolw[rowptr[d] + pos] = make_float2(__int_as_float(s), dis[s] * dis[d]);
    }
}

// ---- GEMM1: z_k = rownorm(x) @ W1[k].  rownorm commutes: (x/S)W = (xW)/S ----
// One wave per row; row wave-uniform (readfirstlane) -> scalar s_load broadcast of x;
// lane's W column pinned in 128 VGPRs. launch_bounds(256,2): VGPR cap 256 -> NO SPILL
// (R4's default cap spilled wr[128] to scratch: VGPR=80, 60us; ~170 VGPR expected here).
__global__ __launch_bounds__(256, 2) void gemm1_kernel(
    const float* __restrict__ x, const float* __restrict__ W1,
    float* __restrict__ z, int n, int nstride)
{
    int lane = threadIdx.x & 63;
    int k = lane >> 4, oo = lane & 15;
    float wr[128];
    #pragma unroll
    for (int d = 0; d < 128; ++d)
        wr[d] = W1[k * 2048 + d * 16 + oo];     // W1[k][d][oo]
    int wid = blockIdx.x * (blockDim.x >> 6) + (threadIdx.x >> 6);
    int nw  = gridDim.x * (blockDim.x >> 6);
    for (int row = wid; row < n; row += nw) {
        int urow = __builtin_amdgcn_readfirstlane(row);
        const float4* xr = (const float4*)(x + (long)urow * 128);
        float acc0 = 0.f, acc1 = 0.f, sum0 = 0.f, sum1 = 0.f;
        #pragma unroll
        for (int j = 0; j < 32; j += 2) {
            float4 a = xr[j], b = xr[j + 1];
            acc0 += a.x * wr[4*j+0] + a.y * wr[4*j+1] + a.z * wr[4*j+2] + a.w * wr[4*j+3];
            acc1 += b.x * wr[4*j+4] + b.y * wr[4*j+5] + b.z * wr[4*j+6] + b.w * wr[4*j+7];
            sum0 += (a.x + a.y) + (a.z + a.w);
            sum1 += (b.x + b.y) + (b.z + b.w);
        }
        float scale = 1.0f / fmaxf(sum0 + sum1, 1e-8f);
        z[(long)k * nstride + (long)urow * 16 + oo] = (acc0 + acc1) * scale;
    }
}

// ---- CSR SpMM (width 16): out[r,:] = sum_e w[e]*in[col[e],:] (+addsrc)(+b)(relu) ----
__global__ __launch_bounds__(256) void spmm_csr_kernel(
    const float* __restrict__ in, const float* __restrict__ addsrc,
    float* __restrict__ out, const int* __restrict__ rowptr,
    const float2* __restrict__ ecolw, const float* __restrict__ b,
    int relu, int n)
{
    int t = blockIdx.x * blockDim.x + threadIdx.x;
    int r = t >> 4, f = t & 15;
    if (r >= n) return;
    int e0 = rowptr[r], e1 = rowptr[r + 1];
    float acc0 = 0.f, acc1 = 0.f, acc2 = 0.f, acc3 = 0.f;
    int e = e0;
    for (; e + 4 <= e1; e += 4) {
        float2 c0 = ecolw[e], c1 = ecolw[e + 1], c2 = ecolw[e + 2], c3 = ecolw[e + 3];
        acc0 += c0.y * in[__float_as_int(c0.x) * 16 + f];
        acc1 += c1.y * in[__float_as_int(c1.x) * 16 + f];
        acc2 += c2.y * in[__float_as_int(c2.x) * 16 + f];
        acc3 += c3.y * in[__float_as_int(c3.x) * 16 + f];
    }
    for (; e < e1; ++e) {
        float2 c0 = ecolw[e];
        acc0 += c0.y * in[__float_as_int(c0.x) * 16 + f];
    }
    float acc = (acc0 + acc1) + (acc2 + acc3);
    if (addsrc) acc += addsrc[r * 16 + f];
    if (b)      acc += b[f];
    if (relu)   acc = fmaxf(acc, 0.f);
    out[r * 16 + f] = acc;
}

// ---- GEMM2: out[n,64] = cat(planes) @ W2cat + b2, scalar-broadcast scheme ----
__global__ __launch_bounds__(256) void gemm2_kernel(
    const float* __restrict__ z, const float* __restrict__ W2,
    const float* __restrict__ b2, float* __restrict__ out, int n, int nstride)
{
    int lane = threadIdx.x & 63;
    float wr[64];
    #pragma unroll
    for (int j = 0; j < 64; ++j) wr[j] = W2[j * 64 + lane];
    float bias = b2[lane];
    int wid = blockIdx.x * (blockDim.x >> 6) + (threadIdx.x >> 6);
    int nw  = gridDim.x * (blockDim.x >> 6);
    for (int row = wid; row < n; row += nw) {
        int urow = __builtin_amdgcn_readfirstlane(row);
        float acc0 = 0.f, acc1 = 0.f;
        #pragma unroll
        for (int p = 0; p < 4; ++p) {
            const float4* zr = (const float4*)(z + (long)p * nstride + (long)urow * 16);
            float4 a = zr[0], bb = zr[1], c = zr[2], d = zr[3];
            acc0 += a.x  * wr[p*16+ 0] + a.y  * wr[p*16+ 1] + a.z  * wr[p*16+ 2] + a.w  * wr[p*16+ 3];
            acc1 += bb.x * wr[p*16+ 4] + bb.y * wr[p*16+ 5] + bb.z * wr[p*16+ 6] + bb.w * wr[p*16+ 7];
            acc0 += c.x  * wr[p*16+ 8] + c.y  * wr[p*16+ 9] + c.z  * wr[p*16+10] + c.w  * wr[p*16+11];
            acc1 += d.x  * wr[p*16+12] + d.y  * wr[p*16+13] + d.z  * wr[p*16+14] + d.w  * wr[p*16+15];
        }
        out[(long)urow * 64 + lane] = acc0 + acc1 + bias;
    }
}

// ---- fallback: edge-parallel atomic SpMM with on-the-fly norm ----
__global__ __launch_bounds__(256) void spmm_atomic_kernel(
    const float* __restrict__ in, float* __restrict__ out,
    const int* __restrict__ src, const int* __restrict__ dst,
    const float* __restrict__ dis, int E)
{
    int t = blockIdx.x * blockDim.x + threadIdx.x;
    int e = t >> 4, f = t & 15;
    if (e < E) {
        int s = src[e], d = dst[e];
        atomicAdd(&out[d * 16 + f], dis[s] * dis[d] * in[s * 16 + f]);
    }
}

__global__ void bias_relu_kernel(float* __restrict__ z0, const float* __restrict__ b, int total) {
    int i = blockIdx.x * blockDim.x + threadIdx.x;
    if (i < total) {
        float v = z0[i] + b[i & 15];
        z0[i] = v > 0.0f ? v : 0.0f;
    }
}

extern "C" void kernel_launch(void* const* d_in, const int* in_sizes, int n_in,
                              void* d_out, int out_size, void* d_ws, size_t ws_size,
                              hipStream_t stream) {
    const float* x   = (const float*)d_in[0];
    const int*   ei  = (const int*)d_in[1];
    const float* W1  = (const float*)d_in[2];
    const float* b1  = (const float*)d_in[3];
    const float* W2  = (const float*)d_in[4];
    const float* bb2 = (const float*)d_in[5];
    float* out = (float*)d_out;

    const int n  = in_sizes[0] / 128;   // 50000
    const int E  = in_sizes[1] / 2;     // 800000
    const int NS = n * 16;

    const int* srcp = ei;
    const int* dstp = ei + E;

    float* ws = (float*)d_ws;
    // layout: deg/dis [n] | rowptr [n+1] | cnt [n] | bsum [1024] | (pad) | z [4*NS] | ecolw [2*E]
    float* deg    = ws;
    int*   rowptr = (int*)(ws + n);
    int*   cnt    = (int*)(ws + 2 * n + 1);
    int*   bsum   = (int*)(ws + 3 * n + 1);
    size_t zoff   = ((size_t)(3 * n + 1 + 1024) + 3) & ~(size_t)3;   // 16B align
    float* z      = ws + zoff;
    float2* ecolw = (float2*)(z + 4 * (size_t)NS);
    size_t need   = (zoff + 4 * (size_t)NS + 2 * (size_t)E) * sizeof(float);

    if (ws_size >= need) {
        // ---------- CSR path ----------
        int nb = (n + 255) / 256;
        hipMemsetAsync(ws, 0, (size_t)(3 * n + 1 + 1024) * sizeof(float), stream);
        deg_kernel<<<(E + 255) / 256, 256, 0, stream>>>(dstp, deg, E);
        if (nb <= 1024) {
            scanA_kernel<<<nb, 256, 0, stream>>>(deg, rowptr, bsum, n);
            scanB_kernel<<<1, 1024, 0, stream>>>(bsum, nb);
            scanC_kernel<<<nb, 256, 0, stream>>>(rowptr, bsum, n);
        } else {
            scan_kernel<<<1, 1024, 0, stream>>>(deg, rowptr, n);
        }
        dis_kernel<<<(n + 255) / 256, 256, 0, stream>>>(deg, n);   // deg -> dis in place
        scatter_kernel<<<(E + 255) / 256, 256, 0, stream>>>(srcp, dstp, deg, rowptr, cnt, ecolw, E);

        gemm1_kernel<<<2048, 256, 0, stream>>>(x, W1, z, n, NS);

        int sb = (16 * n + 255) / 256;
        // Horner layer 1
        spmm_csr_kernel<<<sb, 256, 0, stream>>>(z + 3 * NS, z + 2 * NS, z + 2 * NS, rowptr, ecolw, nullptr, 0, n);
        spmm_csr_kernel<<<sb, 256, 0, stream>>>(z + 2 * NS, z + 1 * NS, z + 1 * NS, rowptr, ecolw, nullptr, 0, n);
        spmm_csr_kernel<<<sb, 256, 0, stream>>>(z + 1 * NS, z,          z,          rowptr, ecolw, b1,      1, n);
        // layer 2 hops
        spmm_csr_kernel<<<sb, 256, 0, stream>>>(z,          nullptr, z + 1 * NS, rowptr, ecolw, nullptr, 0, n);
        spmm_csr_kernel<<<sb, 256, 0, stream>>>(z + 1 * NS, nullptr, z + 2 * NS, rowptr, ecolw, nullptr, 0, n);
        spmm_csr_kernel<<<sb, 256, 0, stream>>>(z + 2 * NS, nullptr, z + 3 * NS, rowptr, ecolw, nullptr, 0, n);

        gemm2_kernel<<<1024, 256, 0, stream>>>(z, W2, bb2, out, n, NS);
    } else {
        // ---------- fallback: atomic path (dis [n] | z [4*NS]) ----------
        float* dis2 = ws;
        size_t z2off = ((size_t)n + 3) & ~(size_t)3;
        float* z2 = ws + z2off;
        hipMemsetAsync(dis2, 0, n * sizeof(float), stream);
        deg_kernel<<<(E + 255) / 256, 256, 0, stream>>>(dstp, dis2, E);
        dis_kernel<<<(n + 255) / 256, 256, 0, stream>>>(dis2, n);
        gemm1_kernel<<<2048, 256, 0, stream>>>(x, W1, z2, n, NS);
        int sb = (16 * E + 255) / 256;
        spmm_atomic_kernel<<<sb, 256, 0, stream>>>(z2 + 3 * NS, z2 + 2 * NS, srcp, dstp, dis2, E);
        spmm_atomic_kernel<<<sb, 256, 0, stream>>>(z2 + 2 * NS, z2 + 1 * NS, srcp, dstp, dis2, E);
        spmm_atomic_kernel<<<sb, 256, 0, stream>>>(z2 + 1 * NS, z2,          srcp, dstp, dis2, E);
        bias_relu_kernel<<<(NS + 255) / 256, 256, 0, stream>>>(z2, b1, NS);
        hipMemsetAsync(z2 + NS, 0, (size_t)3 * NS * sizeof(float), stream);
        spmm_atomic_kernel<<<sb, 256, 0, stream>>>(z2,          z2 + NS,     srcp, dstp, dis2, E);
        spmm_atomic_kernel<<<sb, 256, 0, stream>>>(z2 + NS,     z2 + 2 * NS, srcp, dstp, dis2, E);
        spmm_atomic_kernel<<<sb, 256, 0, stream>>>(z2 + 2 * NS, z2 + 3 * NS, srcp, dstp, dis2, E);
        gemm2_kernel<<<1024, 256, 0, stream>>>(z2, W2, bb2, out, n, NS);
    }
}